// Round 17
// baseline (69.332 us; speedup 1.0000x reference)
//
#include <hip/hip_runtime.h>

// Signed distance transform, N=192^3, exact separable EDT, packed-u16.
//   scan (axis 2): wave-per-line ballot bitmask EDT -> u16 d^2; also emits a
//       per-(x, k-chunk) dirty bit ("any A>1") so p2 can skip clean A-tiles
//       without even staging them (min-plus only decreases -> exact).
//   expansion: outward min-plus on pair-rows (2 k-lines packed lo/hi u16 in
//       u32, v_pk_add/min_u16), exact-radius b32 reads, 8 radii per ballot,
//       exit all d <= (r+8)^2; radii <= 40 processed, else float fallback.
//       Pre-loop exit: all initial d <= 1 -> converged, no reads/writes.
//   512-thread blocks, ONE pair-row chain per wave (measured best).
//   XCD sibling swizzle: tiles sharing 64B lines run 8 block-ids apart.
//   DAG: memset(flags) -> scan -> p2{B | A(flag-gated)} -> p3{A+B ax0; tanh}.
// A = d^2 to nearest zero of x (ws), B = d^2 to nearest nonzero (ws+14MB).
// flags = first 192 u32 of d_out (dead until p3f overwrites the output).

typedef unsigned short u16;
typedef unsigned int   u32;
typedef unsigned long long u64;
typedef u16 u16x2 __attribute__((ext_vector_type(2)));

#define NN    192
#define NN2   (192 * 192)
#define NN3   (192 * 192 * 192)

#define PAIRS 8
#define PADL  40
#define SROW  278            // words: 40 pad + 192 data + 46 pad
#define SENT16 50000
#define SENTPK 0xC350C350u

__device__ __forceinline__ u16x2 pkmin(u16x2 a, u16x2 b) { return __builtin_elementwise_min(a, b); }
__device__ __forceinline__ u16x2 pkmax(u16x2 a, u16x2 b) { return __builtin_elementwise_max(a, b); }
__device__ __forceinline__ u32 pkm32(u32 a, u32 b) {
    return __builtin_bit_cast(u32, pkmin(__builtin_bit_cast(u16x2, a), __builtin_bit_cast(u16x2, b)));
}

// ---------------------------------------------------------------------------
// Scan: wave-parallel 1D binary EDT along contiguous axis via 192-bit masks.
// ---------------------------------------------------------------------------
__device__ __forceinline__ u64 shr_pair(u64 lo, u64 hi, int s) {
    return (lo >> s) | (s ? (hi << ((64 - s) & 63)) : 0ULL);
}
__device__ __forceinline__ int dist3(u64 a0, u64 a1, u64 a2, int s) {
    u64 w0 = shr_pair(a0, a1, s);
    u64 w1 = shr_pair(a1, a2, s);
    u64 w2 = a2 >> s;
    int t0 = w0 ? __builtin_ctzll(w0) : 255;
    int t1 = w1 ? 64 + __builtin_ctzll(w1) : 255;
    int t2 = w2 ? 128 + __builtin_ctzll(w2) : 255;
    int r = t0 < t1 ? t0 : t1;
    return r < t2 ? r : t2;
}
__device__ __forceinline__ void line_edt(u64 m0, u64 m1, u64 m2, int lane,
                                         u16& o0, u16& o1, u16& o2) {
    u64 r0 = __builtin_bitreverse64(m2);
    u64 r1 = __builtin_bitreverse64(m1);
    u64 r2 = __builtin_bitreverse64(m0);
    const int s = lane, t = 63 - lane;
    int f0 = dist3(m0, m1, m2, s);
    int f1 = dist3(m1, m2, 0ULL, s);
    int f2 = dist3(m2, 0ULL, 0ULL, s);
    int b0 = dist3(r2, 0ULL, 0ULL, t);
    int b1 = dist3(r1, r2, 0ULL, t);
    int b2 = dist3(r0, r1, r2, t);
    int d0 = f0 < b0 ? f0 : b0;
    int d1 = f1 < b1 ? f1 : b1;
    int d2 = f2 < b2 ? f2 : b2;
    o0 = (d0 > 191) ? (u16)65535 : (u16)(d0 * d0);
    o1 = (d1 > 191) ? (u16)65535 : (u16)(d1 * d1);
    o2 = (d2 > 191) ? (u16)65535 : (u16)(d2 * d2);
}

__global__ __launch_bounds__(256) void sdt_scan_k(const float* __restrict__ x,
                                                  u16* __restrict__ A,
                                                  u16* __restrict__ B,
                                                  u32* __restrict__ flags) {
    const int lane = threadIdx.x & 63;
    const int wid = blockIdx.x * 4 + (threadIdx.x >> 6);
    const size_t base = (size_t)wid * NN;
    float v0 = x[base + lane];
    float v1 = x[base + lane + 64];
    float v2 = x[base + lane + 128];
    u64 m0 = __ballot(v0 != 0.0f);
    u64 m1 = __ballot(v1 != 0.0f);
    u64 m2 = __ballot(v2 != 0.0f);
    u16 a0, a1, a2, b0, b1, b2;
    line_edt(~m0, ~m1, ~m2, lane, a0, a1, a2);
    line_edt(m0, m1, m2, lane, b0, b1, b2);
    A[base + lane] = a0; A[base + lane + 64] = a1; A[base + lane + 128] = a2;
    B[base + lane] = b0; B[base + lane + 64] = b1; B[base + lane + 128] = b2;

    // dirty map: bit gk of flags[x] = "some A(x, y, k in chunk gk) > 1"
    u64 g0 = __ballot(a0 > (u16)1);
    u64 g1 = __ballot(a1 > (u16)1);
    u64 g2 = __ballot(a2 > (u16)1);
    if (lane == 0) {
        u32 mflag = 0;
#pragma unroll
        for (int c = 0; c < 4; ++c) {
            if ((g0 >> (16 * c)) & 0xFFFFu) mflag |= 1u << c;
            if ((g1 >> (16 * c)) & 0xFFFFu) mflag |= 1u << (c + 4);
            if ((g2 >> (16 * c)) & 0xFFFFu) mflag |= 1u << (c + 8);
        }
        if (mflag) atomicOr(&flags[wid / 192], mflag);
    }
}

// ---------------------------------------------------------------------------
// Tile machinery: 16 k-lines = 8 packed pair-rows per block (512 threads).
// ---------------------------------------------------------------------------
__device__ __forceinline__ void pad_init(u32* ldsw) {
    for (int idx = threadIdx.x; idx < PAIRS * 86; idx += 512) {
        int p = idx / 86, c = idx - p * 86;
        int word = (c < PADL) ? c : (c + NN);
        ldsw[p * SROW + word] = SENTPK;
    }
}

template<long ES>
__device__ __forceinline__ void stage_in(const u16* __restrict__ f, size_t base, u32* ldsw) {
    for (int idx = threadIdx.x; idx < NN * 2; idx += 512) {
        int j = idx >> 1, q = idx & 1;
        uint4 v = *(const uint4*)(f + base + (size_t)j * ES + 8 * q);
        int a = PADL + j;
        ldsw[(4 * q + 0) * SROW + a] = pkm32(v.x, SENTPK);
        ldsw[(4 * q + 1) * SROW + a] = pkm32(v.y, SENTPK);
        ldsw[(4 * q + 2) * SROW + a] = pkm32(v.z, SENTPK);
        ldsw[(4 * q + 3) * SROW + a] = pkm32(v.w, SENTPK);
    }
}

template<long ES>
__device__ __forceinline__ void stage_out(u16* __restrict__ f, size_t base, const u32* ldsw) {
    for (int idx = threadIdx.x; idx < NN * 2; idx += 512) {
        int j = idx >> 1, q = idx & 1;
        int a = PADL + j;
        uint4 v;
        v.x = ldsw[(4 * q + 0) * SROW + a];
        v.y = ldsw[(4 * q + 1) * SROW + a];
        v.z = ldsw[(4 * q + 2) * SROW + a];
        v.w = ldsw[(4 * q + 3) * SROW + a];
        *(uint4*)(f + base + (size_t)j * ES + 8 * q) = v;
    }
}

__device__ __forceinline__ void full_row(const u16x2* rp, int i0, int i1, int i2,
                                         u16x2& d0, u16x2& d1, u16x2& d2) {
    const float fi0 = (float)i0, fi1 = (float)i1, fi2 = (float)i2;
    float e0l = 3e38f, e0h = 3e38f, e1l = 3e38f, e1h = 3e38f, e2l = 3e38f, e2h = 3e38f;
    for (int j = 0; j < NN; ++j) {
        u16x2 gv = rp[j];
        float gl = (float)gv.x, gh = (float)gv.y;
        float jf = (float)j;
        float t0 = jf - fi0, t1 = jf - fi1, t2 = jf - fi2;
        float s0 = t0 * t0, s1 = t1 * t1, s2 = t2 * t2;
        e0l = fminf(e0l, s0 + gl); e0h = fminf(e0h, s0 + gh);
        e1l = fminf(e1l, s1 + gl); e1h = fminf(e1h, s1 + gh);
        e2l = fminf(e2l, s2 + gl); e2h = fminf(e2h, s2 + gh);
    }
    d0.x = (u16)fminf((float)d0.x, e0l); d0.y = (u16)fminf((float)d0.y, e0h);
    d1.x = (u16)fminf((float)d1.x, e1l); d1.y = (u16)fminf((float)d1.y, e1h);
    d2.x = (u16)fminf((float)d2.x, e2l); d2.y = (u16)fminf((float)d2.y, e2h);
}

// Expansion: wave w owns pair-row w; 8 radii per ballot, b32 u16x2 reads,
// wave-uniform packed costs. Pre-loop exit when all initial d <= 1.
__device__ __forceinline__ bool expand_row(u32* rowbase) {
    const int lane = threadIdx.x & 63;
    const int i0 = lane, i1 = lane + 64, i2 = lane + 128;
    u16x2* rp = (u16x2*)rowbase;
    u16x2 d0 = rp[i0], d1 = rp[i1], d2 = rp[i2];

    {
        u16x2 mv = pkmax(pkmax(d0, d1), d2);
        unsigned mm = (mv.x > mv.y) ? mv.x : mv.y;
        if (__all(mm <= 1u)) return false;
    }

    int r = 1;
    bool conv = false;
    while (true) {
#pragma unroll
        for (int m = 0; m < 8; ++m) {
            const int rad = r + m;
            const u16 c = (u16)(rad * rad);
            const u16x2 q = {c, c};
            d0 = pkmin(d0, rp[i0 - rad] + q); d0 = pkmin(d0, rp[i0 + rad] + q);
            d1 = pkmin(d1, rp[i1 - rad] + q); d1 = pkmin(d1, rp[i1 + rad] + q);
            d2 = pkmin(d2, rp[i2 - rad] + q); d2 = pkmin(d2, rp[i2 + rad] + q);
        }
        u16x2 mv = pkmax(pkmax(d0, d1), d2);
        unsigned mm = (mv.x > mv.y) ? mv.x : mv.y;
        unsigned thr = (unsigned)((r + 8) * (r + 8));
        if (__all(mm <= thr)) { conv = true; break; }
        r += 8;
        if (r > 33) break;   // radii <= 40 processed
    }
    if (!conv) {
        u16x2 mv = pkmax(pkmax(d0, d1), d2);
        unsigned mm = (mv.x > mv.y) ? mv.x : mv.y;
        if (__any(mm > 1681u)) {
            full_row(rp, i0, i1, i2, d0, d1, d2);
        }
    }
    // wave owns this row; its reads completed (in-order DS per wave)
    rp[i0] = d0; rp[i1] = d1; rp[i2] = d2;
    return true;
}

// tile-id unswizzle: sibling tiles (even/odd k-chunk pairs sharing 64B lines)
// sit 8 block-ids apart -> same XCD L2. u in [0,2304) -> t in [0,2304).
__device__ __forceinline__ int unswizzle(int u) {
    int blk = u >> 4, rem = u & 15;
    int s = rem >> 3, p7 = rem & 7;
    int pid = blk * 8 + p7;
    return 2 * pid + s;
}

// ---------------------------------------------------------------------------
// p2: in-place ax1 pass; g<2304 -> B tile (heavy, first), else A tile.
// A tiles consult the dirty map: clear bit -> exact no-op, return pre-stage.
// ---------------------------------------------------------------------------
__global__ __launch_bounds__(512, 8) void sdt_p2(u16* __restrict__ A, u16* __restrict__ B,
                                                 const u32* __restrict__ flags) {
    __shared__ __align__(16) u32 ldsw[PAIRS * SROW]; // 8,896 B
    __shared__ int chg;
    int g = blockIdx.x;
    const bool isB = (g < 2304);
    u16* f = isB ? B : A;
    int t = unswizzle(isB ? g : g - 2304);
    const int gp = t / 12, gk = t - 12 * gp;
    if (!isB && !((flags[gp] >> gk) & 1u)) return;  // all A <= 1: exact no-op
    const size_t base = (size_t)gp * NN2 + (size_t)gk * 16;
    if (threadIdx.x == 0) chg = 0;
    pad_init(ldsw);
    stage_in<NN>(f, base, ldsw);
    __syncthreads();
    {
        const int w = threadIdx.x >> 6;
        bool c = expand_row(ldsw + w * SROW + PADL);
        if (c && (threadIdx.x & 63) == 0) chg = 1;
    }
    __syncthreads();
    if (chg) stage_out<NN>(f, base, ldsw);
}

// ---------------------------------------------------------------------------
// p3: fused final pass per 16-k-line slab: expand A ax0 -> regs; expand B ax0
// in same LDS; tanh epilogue writes float out. No field writes.
// ---------------------------------------------------------------------------
__global__ __launch_bounds__(512, 8) void sdt_p3f(u16* __restrict__ B,
                                                  const u16* __restrict__ A,
                                                  float* __restrict__ out) {
    __shared__ __align__(16) u32 ldsw[PAIRS * SROW];
    const int tid = threadIdx.x;
    const int t = unswizzle(blockIdx.x);
    const int gp = t / 12, gk = t - 12 * gp;
    const size_t base = (size_t)gp * NN + (size_t)gk * 16;

    pad_init(ldsw);
    stage_in<NN2>(A, base, ldsw);
    __syncthreads();
    expand_row(ldsw + (tid >> 6) * SROW + PADL);
    __syncthreads();
    uint4 va = {0, 0, 0, 0};
    if (tid < NN * 2) {
        int j = tid >> 1, q = tid & 1, a = PADL + j;
        va.x = ldsw[(4 * q + 0) * SROW + a];
        va.y = ldsw[(4 * q + 1) * SROW + a];
        va.z = ldsw[(4 * q + 2) * SROW + a];
        va.w = ldsw[(4 * q + 3) * SROW + a];
    }
    __syncthreads();
    stage_in<NN2>(B, base, ldsw);
    __syncthreads();
    expand_row(ldsw + (tid >> 6) * SROW + PADL);
    __syncthreads();
    if (tid < NN * 2) {
        int j = tid >> 1, q = tid & 1, a = PADL + j;
        uint4 vb;
        vb.x = ldsw[(4 * q + 0) * SROW + a];
        vb.y = ldsw[(4 * q + 1) * SROW + a];
        vb.z = ldsw[(4 * q + 2) * SROW + a];
        vb.w = ldsw[(4 * q + 3) * SROW + a];
        u32 wa[4] = {va.x, va.y, va.z, va.w};
        u32 wb[4] = {vb.x, vb.y, vb.z, vb.w};
        float o[8];
#pragma unroll
        for (int s = 0; s < 4; ++s) {
            u16x2 A2 = __builtin_bit_cast(u16x2, wa[s]);
            u16x2 B2 = __builtin_bit_cast(u16x2, wb[s]);
            float x0 = (sqrtf((float)A2.x) - sqrtf((float)B2.x)) * 0.1f;
            float x1 = (sqrtf((float)A2.y) - sqrtf((float)B2.y)) * 0.1f;
            float e0 = __expf(2.f * x0);
            float e1 = __expf(2.f * x1);
            o[2 * s]     = 1.f - 2.f * __builtin_amdgcn_rcpf(e0 + 1.f);
            o[2 * s + 1] = 1.f - 2.f * __builtin_amdgcn_rcpf(e1 + 1.f);
        }
        size_t ga = base + (size_t)j * NN2 + 8 * q;
        *(float4*)(out + ga)     = *(float4*)(o);
        *(float4*)(out + ga + 4) = *(float4*)(o + 4);
    }
}

extern "C" void kernel_launch(void* const* d_in, const int* in_sizes, int n_in,
                              void* d_out, int out_size, void* d_ws, size_t ws_size,
                              hipStream_t stream) {
    const float* x = (const float*)d_in[0];
    u16* A = (u16*)d_ws;
    u16* B = (u16*)((char*)d_ws + (size_t)NN3 * 2);
    float* out = (float*)d_out;
    u32* flags = (u32*)d_out;  // dead until p3f overwrites; zeroed each launch

    hipMemsetAsync(flags, 0, NN * sizeof(u32), stream);
    sdt_scan_k<<<NN2 / 4, 256, 0, stream>>>(x, A, B, flags);
    sdt_p2<<<4608, 512, 0, stream>>>(A, B, flags);
    sdt_p3f<<<2304, 512, 0, stream>>>(B, A, out);
}

// Round 18
// 62.502 us; speedup vs baseline: 1.1093x; 1.1093x over previous
//
#include <hip/hip_runtime.h>

// Signed distance transform, N=192^3, exact separable EDT, packed-u16.
// (R16 configuration — measured best: 62.7 us.)
//   scan (axis 2): wave-per-line ballot bitmask EDT -> u16 d^2
//   expansion: outward min-plus on pair-rows (2 k-lines packed lo/hi u16 in
//       u32, v_pk_add/min_u16), exact-radius b32 reads, 8 radii per ballot,
//       exit all d <= (r+8)^2; radii <= 40 processed, else float fallback.
//       PRE-LOOP exit: if all initial d <= 1 no radius can improve (cand >= 1)
//       -> converged with zero neighbor reads (A-field rows ~99%).
//   512-thread blocks, ONE pair-row chain per wave (measured best).
//   p2 A-tiles that saw no change skip stage-out (global already identical).
//   XCD sibling swizzle: tiles sharing 64B lines run 8 block-ids apart.
//   DAG: scan -> p2{B ax1 (first) | A ax1} -> p3{A ax0 -> regs; B ax0; tanh}.
// A = d^2 to nearest zero of x (ws), B = d^2 to nearest nonzero (ws+14MB).

typedef unsigned short u16;
typedef unsigned int   u32;
typedef unsigned long long u64;
typedef u16 u16x2 __attribute__((ext_vector_type(2)));

#define NN    192
#define NN2   (192 * 192)
#define NN3   (192 * 192 * 192)

#define PAIRS 8
#define PADL  40
#define SROW  278            // words: 40 pad + 192 data + 46 pad
#define SENT16 50000
#define SENTPK 0xC350C350u

__device__ __forceinline__ u16x2 pkmin(u16x2 a, u16x2 b) { return __builtin_elementwise_min(a, b); }
__device__ __forceinline__ u16x2 pkmax(u16x2 a, u16x2 b) { return __builtin_elementwise_max(a, b); }
__device__ __forceinline__ u32 pkm32(u32 a, u32 b) {
    return __builtin_bit_cast(u32, pkmin(__builtin_bit_cast(u16x2, a), __builtin_bit_cast(u16x2, b)));
}

// ---------------------------------------------------------------------------
// Scan: wave-parallel 1D binary EDT along contiguous axis via 192-bit masks.
// ---------------------------------------------------------------------------
__device__ __forceinline__ u64 shr_pair(u64 lo, u64 hi, int s) {
    return (lo >> s) | (s ? (hi << ((64 - s) & 63)) : 0ULL);
}
__device__ __forceinline__ int dist3(u64 a0, u64 a1, u64 a2, int s) {
    u64 w0 = shr_pair(a0, a1, s);
    u64 w1 = shr_pair(a1, a2, s);
    u64 w2 = a2 >> s;
    int t0 = w0 ? __builtin_ctzll(w0) : 255;
    int t1 = w1 ? 64 + __builtin_ctzll(w1) : 255;
    int t2 = w2 ? 128 + __builtin_ctzll(w2) : 255;
    int r = t0 < t1 ? t0 : t1;
    return r < t2 ? r : t2;
}
__device__ __forceinline__ void line_edt(u64 m0, u64 m1, u64 m2, int lane,
                                         u16& o0, u16& o1, u16& o2) {
    u64 r0 = __builtin_bitreverse64(m2);
    u64 r1 = __builtin_bitreverse64(m1);
    u64 r2 = __builtin_bitreverse64(m0);
    const int s = lane, t = 63 - lane;
    int f0 = dist3(m0, m1, m2, s);
    int f1 = dist3(m1, m2, 0ULL, s);
    int f2 = dist3(m2, 0ULL, 0ULL, s);
    int b0 = dist3(r2, 0ULL, 0ULL, t);
    int b1 = dist3(r1, r2, 0ULL, t);
    int b2 = dist3(r0, r1, r2, t);
    int d0 = f0 < b0 ? f0 : b0;
    int d1 = f1 < b1 ? f1 : b1;
    int d2 = f2 < b2 ? f2 : b2;
    o0 = (d0 > 191) ? (u16)65535 : (u16)(d0 * d0);
    o1 = (d1 > 191) ? (u16)65535 : (u16)(d1 * d1);
    o2 = (d2 > 191) ? (u16)65535 : (u16)(d2 * d2);
}

__global__ __launch_bounds__(256) void sdt_scan_k(const float* __restrict__ x,
                                                  u16* __restrict__ A,
                                                  u16* __restrict__ B) {
    const int lane = threadIdx.x & 63;
    const int wid = blockIdx.x * 4 + (threadIdx.x >> 6);
    const size_t base = (size_t)wid * NN;
    float v0 = x[base + lane];
    float v1 = x[base + lane + 64];
    float v2 = x[base + lane + 128];
    u64 m0 = __ballot(v0 != 0.0f);
    u64 m1 = __ballot(v1 != 0.0f);
    u64 m2 = __ballot(v2 != 0.0f);
    u16 a0, a1, a2, b0, b1, b2;
    line_edt(~m0, ~m1, ~m2, lane, a0, a1, a2);
    line_edt(m0, m1, m2, lane, b0, b1, b2);
    A[base + lane] = a0; A[base + lane + 64] = a1; A[base + lane + 128] = a2;
    B[base + lane] = b0; B[base + lane + 64] = b1; B[base + lane + 128] = b2;
}

// ---------------------------------------------------------------------------
// Tile machinery: 16 k-lines = 8 packed pair-rows per block (512 threads).
// ---------------------------------------------------------------------------
__device__ __forceinline__ void pad_init(u32* ldsw) {
    for (int idx = threadIdx.x; idx < PAIRS * 86; idx += 512) {
        int p = idx / 86, c = idx - p * 86;
        int word = (c < PADL) ? c : (c + NN);
        ldsw[p * SROW + word] = SENTPK;
    }
}

template<long ES>
__device__ __forceinline__ void stage_in(const u16* __restrict__ f, size_t base, u32* ldsw) {
    for (int idx = threadIdx.x; idx < NN * 2; idx += 512) {
        int j = idx >> 1, q = idx & 1;
        uint4 v = *(const uint4*)(f + base + (size_t)j * ES + 8 * q);
        int a = PADL + j;
        ldsw[(4 * q + 0) * SROW + a] = pkm32(v.x, SENTPK);
        ldsw[(4 * q + 1) * SROW + a] = pkm32(v.y, SENTPK);
        ldsw[(4 * q + 2) * SROW + a] = pkm32(v.z, SENTPK);
        ldsw[(4 * q + 3) * SROW + a] = pkm32(v.w, SENTPK);
    }
}

template<long ES>
__device__ __forceinline__ void stage_out(u16* __restrict__ f, size_t base, const u32* ldsw) {
    for (int idx = threadIdx.x; idx < NN * 2; idx += 512) {
        int j = idx >> 1, q = idx & 1;
        int a = PADL + j;
        uint4 v;
        v.x = ldsw[(4 * q + 0) * SROW + a];
        v.y = ldsw[(4 * q + 1) * SROW + a];
        v.z = ldsw[(4 * q + 2) * SROW + a];
        v.w = ldsw[(4 * q + 3) * SROW + a];
        *(uint4*)(f + base + (size_t)j * ES + 8 * q) = v;
    }
}

__device__ __forceinline__ void full_row(const u16x2* rp, int i0, int i1, int i2,
                                         u16x2& d0, u16x2& d1, u16x2& d2) {
    const float fi0 = (float)i0, fi1 = (float)i1, fi2 = (float)i2;
    float e0l = 3e38f, e0h = 3e38f, e1l = 3e38f, e1h = 3e38f, e2l = 3e38f, e2h = 3e38f;
    for (int j = 0; j < NN; ++j) {
        u16x2 gv = rp[j];
        float gl = (float)gv.x, gh = (float)gv.y;
        float jf = (float)j;
        float t0 = jf - fi0, t1 = jf - fi1, t2 = jf - fi2;
        float s0 = t0 * t0, s1 = t1 * t1, s2 = t2 * t2;
        e0l = fminf(e0l, s0 + gl); e0h = fminf(e0h, s0 + gh);
        e1l = fminf(e1l, s1 + gl); e1h = fminf(e1h, s1 + gh);
        e2l = fminf(e2l, s2 + gl); e2h = fminf(e2h, s2 + gh);
    }
    d0.x = (u16)fminf((float)d0.x, e0l); d0.y = (u16)fminf((float)d0.y, e0h);
    d1.x = (u16)fminf((float)d1.x, e1l); d1.y = (u16)fminf((float)d1.y, e1h);
    d2.x = (u16)fminf((float)d2.x, e2l); d2.y = (u16)fminf((float)d2.y, e2h);
}

// Expansion: wave w owns pair-row w (ONE serial convergence chain per wave);
// 8 radii per ballot, b32 u16x2 reads, wave-uniform packed costs.
// Pre-loop exit: all initial d <= 1 -> candidates (>= 1) can't improve ->
// converged with no neighbor reads and no write-back. Returns "changed".
__device__ __forceinline__ bool expand_row(u32* rowbase) {
    const int lane = threadIdx.x & 63;
    const int i0 = lane, i1 = lane + 64, i2 = lane + 128;
    u16x2* rp = (u16x2*)rowbase;
    u16x2 d0 = rp[i0], d1 = rp[i1], d2 = rp[i2];

    {
        u16x2 mv = pkmax(pkmax(d0, d1), d2);
        unsigned mm = (mv.x > mv.y) ? mv.x : mv.y;
        if (__all(mm <= 1u)) return false;
    }

    int r = 1;
    bool conv = false;
    while (true) {
#pragma unroll
        for (int m = 0; m < 8; ++m) {
            const int rad = r + m;
            const u16 c = (u16)(rad * rad);
            const u16x2 q = {c, c};
            d0 = pkmin(d0, rp[i0 - rad] + q); d0 = pkmin(d0, rp[i0 + rad] + q);
            d1 = pkmin(d1, rp[i1 - rad] + q); d1 = pkmin(d1, rp[i1 + rad] + q);
            d2 = pkmin(d2, rp[i2 - rad] + q); d2 = pkmin(d2, rp[i2 + rad] + q);
        }
        u16x2 mv = pkmax(pkmax(d0, d1), d2);
        unsigned mm = (mv.x > mv.y) ? mv.x : mv.y;
        unsigned thr = (unsigned)((r + 8) * (r + 8));
        if (__all(mm <= thr)) { conv = true; break; }
        r += 8;
        if (r > 33) break;   // radii <= 40 processed
    }
    if (!conv) {
        u16x2 mv = pkmax(pkmax(d0, d1), d2);
        unsigned mm = (mv.x > mv.y) ? mv.x : mv.y;
        if (__any(mm > 1681u)) {
            full_row(rp, i0, i1, i2, d0, d1, d2);
        }
    }
    // wave owns this row; its reads completed (in-order DS per wave)
    rp[i0] = d0; rp[i1] = d1; rp[i2] = d2;
    return true;
}

// tile-id unswizzle: sibling tiles (even/odd k-chunk pairs sharing 64B lines)
// sit 8 block-ids apart -> same XCD L2. u in [0,2304) -> t in [0,2304).
__device__ __forceinline__ int unswizzle(int u) {
    int blk = u >> 4, rem = u & 15;
    int s = rem >> 3, p7 = rem & 7;
    int pid = blk * 8 + p7;
    return 2 * pid + s;
}

// ---------------------------------------------------------------------------
// p2: in-place ax1 pass; g<2304 -> B tile (heavy, first), else A tile.
// Tile t: plane gp = t/12, k-chunk gk = t%12 (16 lines). Unchanged tiles
// (pre-check hit on every row -> global already identical) skip stage-out.
// ---------------------------------------------------------------------------
__global__ __launch_bounds__(512, 8) void sdt_p2(u16* __restrict__ A, u16* __restrict__ B) {
    __shared__ __align__(16) u32 ldsw[PAIRS * SROW]; // 8,896 B
    __shared__ int chg;
    int g = blockIdx.x;
    u16* f = (g < 2304) ? B : A;
    int t = unswizzle((g < 2304) ? g : g - 2304);
    const int gp = t / 12, gk = t - 12 * gp;
    const size_t base = (size_t)gp * NN2 + (size_t)gk * 16;
    if (threadIdx.x == 0) chg = 0;
    pad_init(ldsw);
    stage_in<NN>(f, base, ldsw);
    __syncthreads();
    {
        const int w = threadIdx.x >> 6;
        bool c = expand_row(ldsw + w * SROW + PADL);
        if (c && (threadIdx.x & 63) == 0) chg = 1;
    }
    __syncthreads();
    if (chg) stage_out<NN>(f, base, ldsw);
}

// ---------------------------------------------------------------------------
// p3: fused final pass per 16-k-line slab: expand A ax0 -> regs; expand B ax0
// in same LDS; tanh epilogue writes float out. No field writes.
// ---------------------------------------------------------------------------
__global__ __launch_bounds__(512, 8) void sdt_p3f(u16* __restrict__ B,
                                                  const u16* __restrict__ A,
                                                  float* __restrict__ out) {
    __shared__ __align__(16) u32 ldsw[PAIRS * SROW];
    const int tid = threadIdx.x;
    const int t = unswizzle(blockIdx.x);
    const int gp = t / 12, gk = t - 12 * gp;
    const size_t base = (size_t)gp * NN + (size_t)gk * 16;

    pad_init(ldsw);
    stage_in<NN2>(A, base, ldsw);
    __syncthreads();
    expand_row(ldsw + (tid >> 6) * SROW + PADL);
    __syncthreads();
    uint4 va = {0, 0, 0, 0};
    if (tid < NN * 2) {
        int j = tid >> 1, q = tid & 1, a = PADL + j;
        va.x = ldsw[(4 * q + 0) * SROW + a];
        va.y = ldsw[(4 * q + 1) * SROW + a];
        va.z = ldsw[(4 * q + 2) * SROW + a];
        va.w = ldsw[(4 * q + 3) * SROW + a];
    }
    __syncthreads();
    stage_in<NN2>(B, base, ldsw);
    __syncthreads();
    expand_row(ldsw + (tid >> 6) * SROW + PADL);
    __syncthreads();
    if (tid < NN * 2) {
        int j = tid >> 1, q = tid & 1, a = PADL + j;
        uint4 vb;
        vb.x = ldsw[(4 * q + 0) * SROW + a];
        vb.y = ldsw[(4 * q + 1) * SROW + a];
        vb.z = ldsw[(4 * q + 2) * SROW + a];
        vb.w = ldsw[(4 * q + 3) * SROW + a];
        u32 wa[4] = {va.x, va.y, va.z, va.w};
        u32 wb[4] = {vb.x, vb.y, vb.z, vb.w};
        float o[8];
#pragma unroll
        for (int s = 0; s < 4; ++s) {
            u16x2 A2 = __builtin_bit_cast(u16x2, wa[s]);
            u16x2 B2 = __builtin_bit_cast(u16x2, wb[s]);
            float x0 = (sqrtf((float)A2.x) - sqrtf((float)B2.x)) * 0.1f;
            float x1 = (sqrtf((float)A2.y) - sqrtf((float)B2.y)) * 0.1f;
            float e0 = __expf(2.f * x0);
            float e1 = __expf(2.f * x1);
            o[2 * s]     = 1.f - 2.f * __builtin_amdgcn_rcpf(e0 + 1.f);
            o[2 * s + 1] = 1.f - 2.f * __builtin_amdgcn_rcpf(e1 + 1.f);
        }
        size_t ga = base + (size_t)j * NN2 + 8 * q;
        *(float4*)(out + ga)     = *(float4*)(o);
        *(float4*)(out + ga + 4) = *(float4*)(o + 4);
    }
}

extern "C" void kernel_launch(void* const* d_in, const int* in_sizes, int n_in,
                              void* d_out, int out_size, void* d_ws, size_t ws_size,
                              hipStream_t stream) {
    const float* x = (const float*)d_in[0];
    u16* A = (u16*)d_ws;
    u16* B = (u16*)((char*)d_ws + (size_t)NN3 * 2);
    float* out = (float*)d_out;

    sdt_scan_k<<<NN2 / 4, 256, 0, stream>>>(x, A, B);
    sdt_p2<<<4608, 512, 0, stream>>>(A, B);
    sdt_p3f<<<2304, 512, 0, stream>>>(B, A, out);
}